// Round 1
// baseline (7251.767 us; speedup 1.0000x reference)
//
#include <hip/hip_runtime.h>

typedef unsigned short u16;
typedef __attribute__((ext_vector_type(8))) short short8;
typedef __attribute__((ext_vector_type(4))) float f32x4;

#define L_ 12
#define P_ 20
#define H_ 12
#define E_ 64
#define D_ 768
#define NEXP_ 9
#define B_ 32
#define S_ 512
#define M_TOK 16384  // B_*S_

// ---------- helpers ----------
__device__ __forceinline__ u16 f2b(float f) {
  union { float f; unsigned u; } a; a.f = f;
  unsigned u = a.u;
  unsigned r = (u + 0x7FFFu + ((u >> 16) & 1u)) >> 16;
  return (u16)r;
}

__device__ __forceinline__ float red64_sum(float v) {
  #pragma unroll
  for (int o = 32; o > 0; o >>= 1) v += __shfl_xor(v, o);
  return v;
}
__device__ __forceinline__ float red16_max(float v) {
  v = fmaxf(v, __shfl_xor(v, 1)); v = fmaxf(v, __shfl_xor(v, 2));
  v = fmaxf(v, __shfl_xor(v, 4)); v = fmaxf(v, __shfl_xor(v, 8));
  return v;
}
__device__ __forceinline__ float red16_sum(float v) {
  v += __shfl_xor(v, 1); v += __shfl_xor(v, 2);
  v += __shfl_xor(v, 4); v += __shfl_xor(v, 8);
  return v;
}

__device__ __forceinline__ void gld_lds16(const u16* g, u16* l) {
  __builtin_amdgcn_global_load_lds(
      (const __attribute__((address_space(1))) void*)g,
      (__attribute__((address_space(3))) void*)l, 16, 0, 0);
}

// ---------- gate: per-layer softmax weights + moe partial ----------
__global__ void gate_kernel(const float* __restrict__ expert_emb,
                            const float* __restrict__ gate_w,
                            const float* __restrict__ gate_b,
                            float* __restrict__ wgate, float* __restrict__ moepart) {
  int l = blockIdx.x;
  int tid = threadIdx.x, lane = tid & 63, wave = tid >> 6;
  float acc[NEXP_];
  #pragma unroll
  for (int n = 0; n < NEXP_; n++) acc[n] = 0.f;
  for (int i = tid; i < P_ * D_; i += 256) {
    int p = i / D_, d = i - p * D_;
    float gi = 0.f;
    #pragma unroll
    for (int n = 0; n < NEXP_; n++)
      gi += expert_emb[((size_t)n * P_ + p) * (L_ * 2 * D_) + (size_t)l * (2 * D_) + d];
    const float* gw = gate_w + (size_t)l * (P_ * D_) * NEXP_ + (size_t)i * NEXP_;
    #pragma unroll
    for (int n = 0; n < NEXP_; n++) acc[n] += gi * gw[n];
  }
  #pragma unroll
  for (int n = 0; n < NEXP_; n++) acc[n] = red64_sum(acc[n]);
  __shared__ float red[4][NEXP_];
  if (lane == 0) {
    #pragma unroll
    for (int n = 0; n < NEXP_; n++) red[wave][n] = acc[n];
  }
  __syncthreads();
  if (tid == 0) {
    float dot[NEXP_]; float mx = -1e30f;
    #pragma unroll
    for (int n = 0; n < NEXP_; n++) {
      dot[n] = red[0][n] + red[1][n] + red[2][n] + red[3][n] + gate_b[l * NEXP_ + n];
      mx = fmaxf(mx, dot[n]);
    }
    float se = 0.f;
    #pragma unroll
    for (int n = 0; n < NEXP_; n++) { dot[n] = expf(dot[n] - mx); se += dot[n]; }
    float inv = 1.f / se, m2 = 0.f;
    #pragma unroll
    for (int n = 0; n < NEXP_; n++) {
      float wn = dot[n] * inv; wgate[l * NEXP_ + n] = wn; m2 += wn * wn;
    }
    moepart[l] = m2;
  }
}

// ---------- combine: ck, cv_tmp = expert-weighted sums ----------
__global__ void combine_kernel(const float* __restrict__ expert_emb,
                               const float* __restrict__ wgate,
                               float* __restrict__ ck, float* __restrict__ cvt) {
  int idx = blockIdx.x * 256 + threadIdx.x;  // (l*20+p)*768+d, total 184320
  int d = idx % D_;
  int pl = idx / D_;
  int p = pl % P_, l = pl / P_;
  float sk = 0.f, sv = 0.f;
  #pragma unroll
  for (int n = 0; n < NEXP_; n++) {
    float wn = wgate[l * NEXP_ + n];
    size_t base = ((size_t)n * P_ + p) * (L_ * 2 * D_) + (size_t)l * (2 * D_);
    sk += wn * expert_emb[base + d];
    sv += wn * expert_emb[base + D_ + d];
  }
  ck[idx] = sk; cvt[idx] = sv;
}

// ---------- proj: cv = cvt @ proj_w[l] + proj_b[l] ----------
__global__ void proj_kernel(const float* __restrict__ cvt, const float* __restrict__ proj_w,
                            const float* __restrict__ proj_b, float* __restrict__ cv) {
  int l = blockIdx.x / P_, p = blockIdx.x % P_;
  int tid = threadIdx.x;
  __shared__ float rowv[D_];
  for (int d = tid; d < D_; d += 256) rowv[d] = cvt[((size_t)l * P_ + p) * D_ + d];
  __syncthreads();
  const float* W = proj_w + (size_t)l * D_ * D_;
  for (int n = tid; n < D_; n += 256) {
    float a = proj_b[l * D_ + n];
    for (int k = 0; k < D_; k++) a += rowv[k] * W[(size_t)k * D_ + n];
    cv[((size_t)l * P_ + p) * D_ + n] = a;
  }
}

// ---------- prefix: build padded bf16 prefix K/V [L][H][32][64] ----------
__global__ void prefix_kernel(const float* __restrict__ ck, const float* __restrict__ cv,
                              u16* __restrict__ pk, u16* __restrict__ pv) {
  int idx = blockIdx.x * 256 + threadIdx.x;  // 12*12*32*64 = 294912
  int e = idx & 63;
  int pp = (idx >> 6) & 31;
  int hl = idx >> 11;
  int h = hl % H_, l = hl / H_;
  float kv = 0.f, vv = 0.f;
  if (pp < P_) {
    size_t s = ((size_t)l * P_ + pp) * D_ + h * E_ + e;
    kv = ck[s]; vv = cv[s];
  }
  pk[idx] = f2b(kv); pv[idx] = f2b(vv);
}

// ---------- embedding + LN ----------
__global__ void embed_kernel(const int* __restrict__ ids, const float* __restrict__ we,
                             const float* __restrict__ pe, const float* __restrict__ te,
                             const float* __restrict__ g, const float* __restrict__ bb,
                             float* __restrict__ x32, u16* __restrict__ xbf) {
  int row = blockIdx.x, tid = threadIdx.x;
  int s = row & (S_ - 1);
  int id = ids[row];
  float v[3]; float s1 = 0.f, s2 = 0.f;
  #pragma unroll
  for (int i = 0; i < 3; i++) {
    int d = tid + i * 256;
    float val = we[(size_t)id * D_ + d] + pe[(size_t)s * D_ + d] + te[d];
    v[i] = val; s1 += val; s2 += val * val;
  }
  s1 = red64_sum(s1); s2 = red64_sum(s2);
  __shared__ float rb[8];
  int lane = tid & 63, wave = tid >> 6;
  if (lane == 0) { rb[wave] = s1; rb[4 + wave] = s2; }
  __syncthreads();
  float t1 = rb[0] + rb[1] + rb[2] + rb[3];
  float t2 = rb[4] + rb[5] + rb[6] + rb[7];
  float mean = t1 * (1.f / D_);
  float var = t2 * (1.f / D_) - mean * mean;
  float rstd = 1.f / sqrtf(var + 1e-12f);
  #pragma unroll
  for (int i = 0; i < 3; i++) {
    int d = tid + i * 256;
    float xn = (v[i] - mean) * rstd * g[d] + bb[d];
    size_t o = (size_t)row * D_ + d;
    x32[o] = xn; xbf[o] = f2b(xn);
  }
}

// ---------- LN (reads fp32 y, writes fp32 x + bf16 x) ----------
__global__ void ln_kernel(const float* __restrict__ y, const float* __restrict__ g,
                          const float* __restrict__ bb,
                          float* __restrict__ x32, u16* __restrict__ xbf) {
  int row = blockIdx.x, tid = threadIdx.x;
  float v[3]; float s1 = 0.f, s2 = 0.f;
  #pragma unroll
  for (int i = 0; i < 3; i++) {
    float val = y[(size_t)row * D_ + tid + i * 256];
    v[i] = val; s1 += val; s2 += val * val;
  }
  s1 = red64_sum(s1); s2 = red64_sum(s2);
  __shared__ float rb[8];
  int lane = tid & 63, wave = tid >> 6;
  if (lane == 0) { rb[wave] = s1; rb[4 + wave] = s2; }
  __syncthreads();
  float t1 = rb[0] + rb[1] + rb[2] + rb[3];
  float t2 = rb[4] + rb[5] + rb[6] + rb[7];
  float mean = t1 * (1.f / D_);
  float var = t2 * (1.f / D_) - mean * mean;
  float rstd = 1.f / sqrtf(var + 1e-12f);
  #pragma unroll
  for (int i = 0; i < 3; i++) {
    int d = tid + i * 256;
    float xn = (v[i] - mean) * rstd * g[d] + bb[d];
    size_t o = (size_t)row * D_ + d;
    x32[o] = xn; xbf[o] = f2b(xn);
  }
}

// ---------- transpose fp32 (R,C) -> bf16 (C,R) ----------
__global__ void transpose_bf16(const float* __restrict__ in, u16* __restrict__ out,
                               int R, int C) {
  __shared__ float tile[32][33];
  int tx = threadIdx.x & 31, ty = threadIdx.x >> 5;  // 32x8
  int c0 = blockIdx.x * 32, r0 = blockIdx.y * 32;
  #pragma unroll
  for (int i = 0; i < 4; i++)
    tile[ty + 8 * i][tx] = in[(size_t)(r0 + ty + 8 * i) * C + c0 + tx];
  __syncthreads();
  #pragma unroll
  for (int i = 0; i < 4; i++)
    out[(size_t)(c0 + ty + 8 * i) * R + r0 + tx] = f2b(tile[tx][ty + 8 * i]);
}

// ---------- main GEMM: C = A(bf16 MxK) * BT(bf16 NxK)^T, fused epilogue ----------
// EPI 0: outY = acc + bias + res (fp32)
// EPI 1: outB = bf16(gelu(acc + bias))
// EPI 2: scatter q/k/v bf16 [B][H][S][E]
template <int EPI>
__global__ __launch_bounds__(256, 2)
void gemm_bf16(const u16* __restrict__ A, const u16* __restrict__ BT,
               const float* __restrict__ bias, const float* __restrict__ res,
               float* __restrict__ outY, u16* __restrict__ outB,
               u16* __restrict__ outQ, u16* __restrict__ outK, u16* __restrict__ outV,
               int M, int N, int K) {
  __shared__ u16 As[4096];
  __shared__ u16 Bs[4096];
  int tid = threadIdx.x;
  int lane = tid & 63, wave = tid >> 6;
  int l15 = lane & 15, lg = lane >> 4;
  int m0 = blockIdx.x * 128, n0 = blockIdx.y * 128;
  int wr = wave >> 1, wc = wave & 1;

  const f32x4 fz = {0.f, 0.f, 0.f, 0.f};
  f32x4 acc[4][4];
  #pragma unroll
  for (int i = 0; i < 4; i++)
    #pragma unroll
    for (int j = 0; j < 4; j++) acc[i][j] = fz;

  int arow = tid >> 2;
  int akc = (tid & 3) * 8;
  const u16* Ab0 = A + (size_t)(m0 + arow) * K + akc;
  const u16* Ab1 = A + (size_t)(m0 + 64 + arow) * K + akc;
  const u16* Bb0 = BT + (size_t)(n0 + arow) * K + akc;
  const u16* Bb1 = BT + (size_t)(n0 + 64 + arow) * K + akc;
  u16* AsW = As + (tid & ~63) * 8;  // wave-uniform LDS base (lane*16B added by HW)
  u16* BsW = Bs + (tid & ~63) * 8;

  int aoff[4], boff[4];
  #pragma unroll
  for (int i = 0; i < 4; i++) {
    aoff[i] = (wr * 64 + i * 16 + l15) * 32 + lg * 8;
    boff[i] = (wc * 64 + i * 16 + l15) * 32 + lg * 8;
  }

  for (int k0 = 0; k0 < K; k0 += 32) {
    gld_lds16(Ab0, AsW);
    gld_lds16(Ab1, AsW + 2048);
    gld_lds16(Bb0, BsW);
    gld_lds16(Bb1, BsW + 2048);
    Ab0 += 32; Ab1 += 32; Bb0 += 32; Bb1 += 32;
    __syncthreads();
    short8 af[4], bfr[4];
    #pragma unroll
    for (int i = 0; i < 4; i++) {
      af[i] = *(const short8*)&As[aoff[i]];
      bfr[i] = *(const short8*)&Bs[boff[i]];
    }
    #pragma unroll
    for (int i = 0; i < 4; i++)
      #pragma unroll
      for (int j = 0; j < 4; j++)
        acc[i][j] = __builtin_amdgcn_mfma_f32_16x16x32_bf16(af[i], bfr[j], acc[i][j], 0, 0, 0);
    __syncthreads();
  }

  int rbase = m0 + wr * 64 + lg * 4;
  int cbase = n0 + wc * 64 + l15;
  #pragma unroll
  for (int i = 0; i < 4; i++) {
    #pragma unroll
    for (int j = 0; j < 4; j++) {
      int col = cbase + j * 16;
      float bv = bias[col];
      #pragma unroll
      for (int r = 0; r < 4; r++) {
        int row = rbase + i * 16 + r;
        float v = acc[i][j][r] + bv;
        if (EPI == 0) {
          size_t o = (size_t)row * N + col;
          outY[o] = v + res[o];
        } else if (EPI == 1) {
          float gg = 0.5f * v * (1.0f + erff(v * 0.70710678118654752f));
          outB[(size_t)row * N + col] = f2b(gg);
        } else {
          int part = col / D_;
          int jj = col - part * D_;
          int h = jj >> 6, e = jj & 63;
          int b = row >> 9, s = row & (S_ - 1);
          u16* dst = (part == 0) ? outQ : ((part == 1) ? outK : outV);
          dst[(((size_t)(b * H_ + h) * S_) + s) * E_ + e] = f2b(v);
        }
      }
    }
  }
}

// ---------- flash attention with 32-slot padded prefix ----------
__global__ __launch_bounds__(256, 2)
void attn_kernel(const u16* __restrict__ q_bf, const u16* __restrict__ k_bf,
                 const u16* __restrict__ v_bf, const u16* __restrict__ pk,
                 const u16* __restrict__ pv, const float* __restrict__ mask,
                 u16* __restrict__ ctx) {
  int bx = blockIdx.x;
  int qt = bx & 7, bh = bx >> 3;
  int b = bh / H_, h = bh - b * H_;
  int tid = threadIdx.x, lane = tid & 63, wave = tid >> 6;
  int l15 = lane & 15, lg = lane >> 4;

  __shared__ u16 P[4][16 * 40];
  __shared__ u16 Vt[64 * 40];

  size_t kvbase = (size_t)(b * H_ + h) * S_ * E_;
  int qrow = qt * 64 + wave * 16 + l15;
  short8 qf[2];
  qf[0] = *(const short8*)&q_bf[kvbase + (size_t)qrow * E_ + lg * 8];
  qf[1] = *(const short8*)&q_bf[kvbase + (size_t)qrow * E_ + 32 + lg * 8];

  float mrow[4] = {-1e30f, -1e30f, -1e30f, -1e30f};
  float lrow[4] = {0.f, 0.f, 0.f, 0.f};
  const f32x4 fz = {0.f, 0.f, 0.f, 0.f};
  f32x4 O[4];
  #pragma unroll
  for (int f2 = 0; f2 < 4; f2++) O[f2] = fz;

  for (int kt = 0; kt < 17; kt++) {
    // stage V^T tile into LDS
    {
      int key = tid >> 3, e0 = (tid & 7) * 8;
      short8 vv;
      if (kt == 0) vv = *(const short8*)&pv[((size_t)h * 32 + key) * E_ + e0];
      else         vv = *(const short8*)&v_bf[kvbase + ((size_t)((kt - 1) * 32 + key)) * E_ + e0];
      u16* vp = (u16*)&vv;
      #pragma unroll
      for (int j = 0; j < 8; j++) Vt[(e0 + j) * 40 + key] = vp[j];
    }
    // scores: Q (16x64) . K^T (64x32)
    f32x4 sa[2];
    #pragma unroll
    for (int f = 0; f < 2; f++) {
      sa[f] = fz;
      const u16* kr;
      if (kt == 0) kr = &pk[((size_t)h * 32 + f * 16 + l15) * E_];
      else         kr = &k_bf[kvbase + ((size_t)((kt - 1) * 32 + f * 16 + l15)) * E_];
      short8 kf0 = *(const short8*)&kr[lg * 8];
      short8 kf1 = *(const short8*)&kr[32 + lg * 8];
      sa[f] = __builtin_amdgcn_mfma_f32_16x16x32_bf16(qf[0], kf0, sa[f], 0, 0, 0);
      sa[f] = __builtin_amdgcn_mfma_f32_16x16x32_bf16(qf[1], kf1, sa[f], 0, 0, 0);
    }
    float bv[2];
    if (kt == 0) {
      bv[0] = (l15 < P_) ? 0.f : -1e30f;
      bv[1] = (16 + l15 < P_) ? 0.f : -1e30f;
    } else {
      int ks = (kt - 1) * 32;
      bv[0] = (1.f - mask[(size_t)b * S_ + ks + l15]) * -10000.f;
      bv[1] = (1.f - mask[(size_t)b * S_ + ks + 16 + l15]) * -10000.f;
    }
    float pcur[2][4], facr[4];
    #pragma unroll
    for (int r = 0; r < 4; r++) {
      float s0 = sa[0][r] * 0.125f + bv[0];
      float s1 = sa[1][r] * 0.125f + bv[1];
      float tm = red16_max(fmaxf(s0, s1));
      float mnew = fmaxf(mrow[r], tm);
      float fac = __expf(mrow[r] - mnew);
      mrow[r] = mnew;
      float p0 = __expf(s0 - mnew);
      float p1 = __expf(s1 - mnew);
      pcur[0][r] = p0; pcur[1][r] = p1;
      float rs = red16_sum(p0 + p1);
      lrow[r] = lrow[r] * fac + rs;
      facr[r] = fac;
    }
    #pragma unroll
    for (int f2 = 0; f2 < 4; f2++)
      #pragma unroll
      for (int r = 0; r < 4; r++) O[f2][r] *= facr[r];
    // write P tile (per-wave region)
    #pragma unroll
    for (int f = 0; f < 2; f++)
      #pragma unroll
      for (int r = 0; r < 4; r++)
        P[wave][(lg * 4 + r) * 40 + f * 16 + l15] = f2b(pcur[f][r]);
    __syncthreads();
    // PV: P (16x32) . V (32x64)
    short8 pa = *(const short8*)&P[wave][l15 * 40 + lg * 8];
    #pragma unroll
    for (int f2 = 0; f2 < 4; f2++) {
      short8 vb = *(const short8*)&Vt[(f2 * 16 + l15) * 40 + lg * 8];
      O[f2] = __builtin_amdgcn_mfma_f32_16x16x32_bf16(pa, vb, O[f2], 0, 0, 0);
    }
    __syncthreads();
  }
  #pragma unroll
  for (int f2 = 0; f2 < 4; f2++) {
    #pragma unroll
    for (int r = 0; r < 4; r++) {
      int row = qt * 64 + wave * 16 + lg * 4 + r;
      int e = f2 * 16 + l15;
      float val = O[f2][r] / lrow[r];
      ctx[((size_t)(b * S_ + row)) * D_ + h * E_ + e] = f2b(val);
    }
  }
}

// ---------- pooler + logits + moe ----------
__global__ void pool_kernel(const float* __restrict__ x32, const float* __restrict__ pw,
                            const float* __restrict__ pb, const float* __restrict__ fcw,
                            const float* __restrict__ fcb, const float* __restrict__ moepart,
                            float* __restrict__ out) {
  int b = blockIdx.x, tid = threadIdx.x;
  __shared__ float rowv[D_];
  __shared__ float pooled[D_];
  for (int d = tid; d < D_; d += 256) rowv[d] = x32[((size_t)b * S_) * D_ + d];
  __syncthreads();
  for (int j = tid; j < D_; j += 256) {
    float a = pb[j];
    for (int k = 0; k < D_; k++) a += rowv[k] * pw[(size_t)k * D_ + j];
    pooled[j] = tanhf(a);
  }
  __syncthreads();
  float p0 = 0.f, p1 = 0.f;
  for (int j = tid; j < D_; j += 256) {
    float pj = pooled[j];
    p0 += pj * fcw[j * 2];
    p1 += pj * fcw[j * 2 + 1];
  }
  p0 = red64_sum(p0); p1 = red64_sum(p1);
  __shared__ float rr[8];
  int lane = tid & 63, wave = tid >> 6;
  if (lane == 0) { rr[wave] = p0; rr[4 + wave] = p1; }
  __syncthreads();
  if (tid == 0) {
    out[b * 2 + 0] = rr[0] + rr[1] + rr[2] + rr[3] + fcb[0];
    out[b * 2 + 1] = rr[4] + rr[5] + rr[6] + rr[7] + fcb[1];
    if (b == 0) {
      float m = 0.f;
      for (int l = 0; l < L_; l++) m += moepart[l];
      out[B_ * 2] = m / (float)L_;
    }
  }
}

// ---------- host ----------
extern "C" void kernel_launch(void* const* d_in, const int* in_sizes, int n_in,
                              void* d_out, int out_size, void* d_ws, size_t ws_size,
                              hipStream_t stream) {
  const int* ids = (const int*)d_in[0];
  const float* amask = (const float*)d_in[1];
  const float* expert_emb = (const float*)d_in[2];
  const float* gate_w = (const float*)d_in[3];
  const float* gate_b = (const float*)d_in[4];
  const float* proj_w = (const float*)d_in[5];
  const float* proj_b = (const float*)d_in[6];
  const float* word_emb = (const float*)d_in[7];
  const float* pos_emb = (const float*)d_in[8];
  const float* type_emb = (const float*)d_in[9];
  const float* eg = (const float*)d_in[10];
  const float* eb = (const float*)d_in[11];
  const float* qkv_w = (const float*)d_in[12];
  const float* qkv_b = (const float*)d_in[13];
  const float* ao_w = (const float*)d_in[14];
  const float* ao_b = (const float*)d_in[15];
  const float* ln1g = (const float*)d_in[16];
  const float* ln1b = (const float*)d_in[17];
  const float* f1w = (const float*)d_in[18];
  const float* f1b = (const float*)d_in[19];
  const float* f2w = (const float*)d_in[20];
  const float* f2bb = (const float*)d_in[21];
  const float* ln2g = (const float*)d_in[22];
  const float* ln2b = (const float*)d_in[23];
  const float* pw = (const float*)d_in[24];
  const float* pb = (const float*)d_in[25];
  const float* fcw = (const float*)d_in[26];
  const float* fcb = (const float*)d_in[27];
  float* out = (float*)d_out;

  char* ws = (char*)d_ws;
  size_t off = 0;
  auto alloc = [&](size_t bytes) -> char* {
    char* p = ws + off;
    off += (bytes + 255) & ~(size_t)255;
    return p;
  };
  float* wgate = (float*)alloc(L_ * NEXP_ * 4);
  float* moepart = (float*)alloc(L_ * 4);
  float* ck = (float*)alloc((size_t)L_ * P_ * D_ * 4);
  float* cvt = (float*)alloc((size_t)L_ * P_ * D_ * 4);
  float* cv = (float*)alloc((size_t)L_ * P_ * D_ * 4);
  u16* pk = (u16*)alloc((size_t)L_ * H_ * 32 * E_ * 2);
  u16* pv = (u16*)alloc((size_t)L_ * H_ * 32 * E_ * 2);
  float* x32 = (float*)alloc((size_t)M_TOK * D_ * 4);
  float* y32 = (float*)alloc((size_t)M_TOK * D_ * 4);
  u16* xbf = (u16*)alloc((size_t)M_TOK * D_ * 2);
  u16* ctx = (u16*)alloc((size_t)M_TOK * D_ * 2);
  u16* qb = (u16*)alloc((size_t)M_TOK * D_ * 2);
  u16* kb = (u16*)alloc((size_t)M_TOK * D_ * 2);
  u16* vb = (u16*)alloc((size_t)M_TOK * D_ * 2);
  u16* hb = (u16*)alloc((size_t)M_TOK * 3072 * 2);
  u16* wtq = (u16*)alloc((size_t)2304 * D_ * 2);
  u16* wta = (u16*)alloc((size_t)D_ * D_ * 2);
  u16* wt1 = (u16*)alloc((size_t)3072 * D_ * 2);
  u16* wt2 = (u16*)alloc((size_t)D_ * 3072 * 2);

  gate_kernel<<<L_, 256, 0, stream>>>(expert_emb, gate_w, gate_b, wgate, moepart);
  combine_kernel<<<(L_ * P_ * D_) / 256, 256, 0, stream>>>(expert_emb, wgate, ck, cvt);
  proj_kernel<<<L_ * P_, 256, 0, stream>>>(cvt, proj_w, proj_b, cv);
  prefix_kernel<<<(L_ * H_ * 32 * E_) / 256, 256, 0, stream>>>(ck, cv, pk, pv);
  embed_kernel<<<M_TOK, 256, 0, stream>>>(ids, word_emb, pos_emb, type_emb, eg, eb, x32, xbf);

  for (int l = 0; l < L_; l++) {
    transpose_bf16<<<dim3(72, 24), 256, 0, stream>>>(qkv_w + (size_t)l * D_ * 2304, wtq, D_, 2304);
    transpose_bf16<<<dim3(24, 24), 256, 0, stream>>>(ao_w + (size_t)l * D_ * D_, wta, D_, D_);
    transpose_bf16<<<dim3(96, 24), 256, 0, stream>>>(f1w + (size_t)l * D_ * 3072, wt1, D_, 3072);
    transpose_bf16<<<dim3(24, 96), 256, 0, stream>>>(f2w + (size_t)l * 3072 * D_, wt2, 3072, D_);

    gemm_bf16<2><<<dim3(128, 18), 256, 0, stream>>>(
        xbf, wtq, qkv_b + (size_t)l * 2304, nullptr, nullptr, nullptr,
        qb, kb, vb, M_TOK, 2304, D_);
    attn_kernel<<<B_ * H_ * 8, 256, 0, stream>>>(
        qb, kb, vb, pk + (size_t)l * H_ * 32 * E_, pv + (size_t)l * H_ * 32 * E_, amask, ctx);
    gemm_bf16<0><<<dim3(128, 6), 256, 0, stream>>>(
        ctx, wta, ao_b + (size_t)l * D_, x32, y32, nullptr,
        nullptr, nullptr, nullptr, M_TOK, D_, D_);
    ln_kernel<<<M_TOK, 256, 0, stream>>>(y32, ln1g + (size_t)l * D_, ln1b + (size_t)l * D_, x32, xbf);
    gemm_bf16<1><<<dim3(128, 24), 256, 0, stream>>>(
        xbf, wt1, f1b + (size_t)l * 3072, nullptr, nullptr, hb,
        nullptr, nullptr, nullptr, M_TOK, 3072, D_);
    gemm_bf16<0><<<dim3(128, 6), 256, 0, stream>>>(
        hb, wt2, f2bb + (size_t)l * D_, x32, y32, nullptr,
        nullptr, nullptr, nullptr, M_TOK, D_, 3072);
    ln_kernel<<<M_TOK, 256, 0, stream>>>(y32, ln2g + (size_t)l * D_, ln2b + (size_t)l * D_, x32, xbf);
  }
  pool_kernel<<<B_, 256, 0, stream>>>(x32, pw, pb, fcw, fcb, moepart, out);
}